// Round 3
// baseline (638.855 us; speedup 1.0000x reference)
//
#include <hip/hip_runtime.h>
#include <hip/hip_bf16.h>

// RecursiveNet bf16-MFMA, round 6b: attack the random-gather memory path.
//   Evidence (r5 rocprof): pair(0,1) = 162 us at 1.07 TB/s HBM, MfmaUtil 15%,
//   VALUBusy 32%, occupancy 22% -> memory-system-limited random gather of
//   512-B fp32 rows. Fix: sequential convert pass x(fp32,256MB,NT-read) ->
//   Gx(bf16,128MB, regular stores => L3-resident), then gather 256-B rows
//   from Gx (half the bytes, served from Infinity Cache).
//   Also: staging loses fp32->bf16 pack VALU; tail_fused 512 thr (8 waves);
//   setprio reverted (r5 net-negative); bias+repack merged into prep_kernel.
//   (r6b: fix nontemporal_load arg type + unsigned min subscript.)

typedef __bf16 v8bf __attribute__((ext_vector_type(8)));
typedef float v16f __attribute__((ext_vector_type(16)));
typedef float v4f __attribute__((ext_vector_type(4)));

__device__ __forceinline__ ushort f2bf(float f) {
    __hip_bfloat16 h = __float2bfloat16(f);
    return *reinterpret_cast<ushort*>(&h);
}
__device__ __forceinline__ unsigned pack2(float lo, float hi) {
    return (unsigned)f2bf(lo) | ((unsigned)f2bf(hi) << 16);
}
__device__ __forceinline__ float leaky(float y) { return (y >= 0.f) ? y : 0.2f * y; }

#define ZACC {0.f,0.f,0.f,0.f,0.f,0.f,0.f,0.f,0.f,0.f,0.f,0.f,0.f,0.f,0.f,0.f}

// ---------------------------------------------------------------------------
// prep: blocks 0..17 -> effective bias per depth row; blocks 18..145 -> A repack
__global__ __launch_bounds__(256)
void prep_kernel(const float* __restrict__ W, const float* __restrict__ b,
                 const float* __restrict__ depth, float* __restrict__ Bst,
                 ushort* __restrict__ A) {
    if (blockIdx.x < 18) {
        if (threadIdx.x < 128) {
            int i = blockIdx.x, o = threadIdx.x;
            const float* Wo = W + (size_t)o * 512 + 256;
            const float* di = depth + (size_t)i * 128;
            float s = b[o];
#pragma unroll 8
            for (int c = 0; c < 128; ++c) s += di[c] * (Wo[2 * c] + Wo[2 * c + 1]);
            Bst[i * 128 + o] = s;
        }
    } else {
        int o = blockIdx.x - 18, c = threadIdx.x;
        float v = (c < 128) ? W[(size_t)o * 512 + 2 * c]
                            : W[(size_t)o * 512 + 2 * (c - 128) + 1];
        A[o * 256 + c] = f2bf(v);
    }
}

// ---------------------------------------------------------------------------
// Sequential fp32 -> bf16 convert. NT loads: x must NOT evict Gx from L3.
__global__ __launch_bounds__(256)
void convert_kernel(const float* __restrict__ x, ushort* __restrict__ Gx) {
    const size_t nchunk = (size_t)524288 * 16;  // chunks of 8 floats
    const size_t stride = (size_t)gridDim.x * 256;
    size_t i = (size_t)blockIdx.x * 256 + threadIdx.x;
#pragma unroll 4
    for (; i < nchunk; i += stride) {
        const v4f* src = (const v4f*)(x + i * 8);
        v4f a = __builtin_nontemporal_load(src);
        v4f c = __builtin_nontemporal_load(src + 1);
        uint4 v;
        v.x = pack2(a.x, a.y);  v.y = pack2(a.z, a.w);
        v.z = pack2(c.x, c.y);  v.w = pack2(c.z, c.w);
        *(uint4*)(Gx + i * 8) = v;
    }
}

// ---------------------------------------------------------------------------
#define WAVE_FRAG(WCH)                                                        \
    v8bf af[16];                                                              \
    {                                                                         \
        const ushort* Arow = A + (size_t)((WCH) * 32 + n31) * 256 + h * 8;    \
        _Pragma("unroll")                                                     \
        for (int s = 0; s < 16; ++s) af[s] = *(const v8bf*)&Arow[s * 16];     \
    }

#define LOAD_BIAS(dst_, Bs, WCH)                                              \
    float dst_[16];                                                           \
    _Pragma("unroll")                                                         \
    for (int r = 0; r < 16; ++r)                                              \
        dst_[r] = (Bs)[(WCH) * 32 + (r & 3) + 8 * (r >> 2) + 4 * h];

// 16 MFMA from a swizzled LDS tile, two independent 8-deep chains.
#define MFMA_TILE_LDS(buf, r0_, r1_, acc)                                     \
    {                                                                         \
        const ushort* sp0 = (buf) + (r0_) * 128;                              \
        const ushort* sp1 = (buf) + (r1_) * 128;                              \
        const int mm0 = (r0_) & 15, mm1 = (r1_) & 15;                         \
        v16f accB_ = ZACC;                                                    \
        _Pragma("unroll")                                                     \
        for (int s = 0; s < 8; ++s) {                                         \
            acc = __builtin_amdgcn_mfma_f32_32x32x16_bf16(                    \
                af[s], *(const v8bf*)&sp0[((2 * s + h) ^ mm0) * 8], acc, 0, 0, 0); \
            accB_ = __builtin_amdgcn_mfma_f32_32x32x16_bf16(                  \
                af[8 + s], *(const v8bf*)&sp1[((2 * s + h) ^ mm1) * 8], accB_, 0, 0, 0); \
        }                                                                     \
        acc += accB_;                                                         \
    }

// ---------------------------------------------------------------------------
// Fused pair of stages. Block -> 32 outputs of the second stage.
// All inputs bf16 now; perm != nullptr selects gather mode (first pair).
__global__ __launch_bounds__(256)
void pair_fused(const ushort* __restrict__ Xin,   // bf16 [Lin][128]
                const int* __restrict__ perm,     // [N] or nullptr
                const ushort* __restrict__ A,     // bf16 [128][256]
                const float* __restrict__ Bst2,   // fp32 [2][128]
                ushort* __restrict__ Y,           // bf16 [Lp2][128]
                int Lin, int Lp2) {
    __shared__ __align__(16) ushort xin[132 * 128];  // 33 KB
    __shared__ __align__(16) ushort mid[65 * 128];   // 16.6 KB
    __shared__ int prow[132];

    const int U = blockIdx.x * 32;
    const int t0 = U * 4;

    if (perm) {
        int tix = threadIdx.x;
        if (tix < 132) prow[tix] = perm[min(t0 + tix, Lin - 1)];
        __syncthreads();
    }
    // batched row loads (9 in flight/thread), then LDS writes
    uint4 vv[9];
#pragma unroll
    for (int k = 0; k < 9; ++k) {
        int idx = (int)threadIdx.x + 256 * k;
        if (idx < 132 * 16) {
            int row = idx >> 4;
            int rs = perm ? prow[row] : min(t0 + row, Lin - 1);
            vv[k] = *(const uint4*)&Xin[(size_t)rs * 128 + (idx & 15) * 8];
        }
    }
#pragma unroll
    for (int k = 0; k < 9; ++k) {
        int idx = (int)threadIdx.x + 256 * k;
        if (idx < 132 * 16) {
            int row = idx >> 4, ck = idx & 15;
            *(uint4*)&xin[row * 128 + ((ck ^ (row & 15)) * 8)] = vv[k];
        }
    }
    __syncthreads();

    const int lane = threadIdx.x & 63;
    const int w = threadIdx.x >> 6;
    const int n31 = lane & 31;
    const int h = lane >> 5;
    WAVE_FRAG(w);

    // ---- stage A: 5 tiles -> mid (LDS)
    {
        LOAD_BIAS(bias_r, Bst2, w);
#pragma unroll
        for (int ti = 0; ti < 5; ++ti) {
            const int p = 32 * ti + n31;
            const int r0 = min(p, 131), r1 = min(p + 1, 131);
            v16f acc = ZACC;
            MFMA_TILE_LDS(xin, r0, r1, acc);
            const int u1 = 16 * ti + (n31 >> 1);
            const bool act = !(lane & 1) && (u1 < 65);
#pragma unroll
            for (int q = 0; q < 4; ++q) {
                float pv[4];
#pragma unroll
                for (int j = 0; j < 4; ++j) {
                    float y = leaky(acc[4 * q + j] + bias_r[4 * q + j]);
                    float y2 = __shfl_xor(y, 1, 64);
                    pv[j] = fmaxf(y, y2);
                }
                if (act) {
                    uint2 v;
                    v.x = pack2(pv[0], pv[1]);
                    v.y = pack2(pv[2], pv[3]);
                    *(uint2*)&mid[u1 * 128 + (((4 * w + q) ^ (u1 & 15)) * 8) + 4 * h] = v;
                }
            }
        }
    }
    __syncthreads();

    // ---- stage B: 2 tiles -> global
    {
        LOAD_BIAS(bias_r, Bst2 + 128, w);
#pragma unroll
        for (int ti = 0; ti < 2; ++ti) {
            const int p = 32 * ti + n31;
            v16f acc = ZACC;
            MFMA_TILE_LDS(mid, p, p + 1, acc);
            const int u2 = U + 16 * ti + (n31 >> 1);
            const bool act = !(lane & 1) && (u2 < Lp2);
#pragma unroll
            for (int q = 0; q < 4; ++q) {
                float pv[4];
#pragma unroll
                for (int j = 0; j < 4; ++j) {
                    float y = leaky(acc[4 * q + j] + bias_r[4 * q + j]);
                    float y2 = __shfl_xor(y, 1, 64);
                    pv[j] = fmaxf(y, y2);
                }
                if (act) {
                    uint2 v;
                    v.x = pack2(pv[0], pv[1]);
                    v.y = pack2(pv[2], pv[3]);
                    *(uint2*)&Y[(size_t)u2 * 128 + w * 32 + 8 * q + 4 * h] = v;
                }
            }
        }
    }
}

// ---------------------------------------------------------------------------
// Stages 10..17 fused (Lin = 511 -> 1), one block, 8 waves, LDS ping-pong.
// Waves split by tile parity (wp) x channel quad (wq).
__global__ __launch_bounds__(512)
void tail_fused(const ushort* __restrict__ Xg, const ushort* __restrict__ A,
                const float* __restrict__ BstAll, float* __restrict__ out) {
    extern __shared__ __align__(16) ushort tbuf[];
    ushort* buf0 = tbuf;              // 255 rows
    ushort* buf1 = tbuf + 255 * 128;  // 127 rows

    const int lane = threadIdx.x & 63;
    const int w = threadIdx.x >> 6;   // 0..7
    const int wq = w & 3;             // channel quad
    const int wp = w >> 2;            // tile parity
    const int n31 = lane & 31;
    const int h = lane >> 5;
    WAVE_FRAG(wq);

    int Lin = 511;
    for (int st = 0; st < 8; ++st) {
        const int Lp = (Lin - 1) >> 1;
        LOAD_BIAS(bias_r, BstAll + (size_t)(10 + st) * 128, wq);
        ushort* dst = (st & 1) ? buf1 : buf0;
        const ushort* src = (st & 1) ? buf0 : buf1;  // unused for st==0
        const int ntiles = (Lin - 1 + 31) >> 5;
        for (int ti = wp; ti < ntiles; ti += 2) {
            const int t = ti * 32 + n31;
            const int r0 = min(t, Lin - 1), r1 = min(t + 1, Lin - 1);
            v16f acc = ZACC;
            if (st == 0) {
                const ushort* p0 = Xg + (size_t)r0 * 128 + h * 8;
                const ushort* p1 = Xg + (size_t)r1 * 128 + h * 8;
                v16f accB = ZACC;
#pragma unroll
                for (int s = 0; s < 8; ++s) {
                    acc = __builtin_amdgcn_mfma_f32_32x32x16_bf16(
                        af[s], *(const v8bf*)&p0[s * 16], acc, 0, 0, 0);
                    accB = __builtin_amdgcn_mfma_f32_32x32x16_bf16(
                        af[8 + s], *(const v8bf*)&p1[s * 16], accB, 0, 0, 0);
                }
                acc += accB;
            } else {
                MFMA_TILE_LDS(src, r0, r1, acc);
            }
            const int u = t >> 1;
            const bool act = !(lane & 1) && (u < Lp);
#pragma unroll
            for (int q = 0; q < 4; ++q) {
                float pv[4];
#pragma unroll
                for (int j = 0; j < 4; ++j) {
                    float y = leaky(acc[4 * q + j] + bias_r[4 * q + j]);
                    float y2 = __shfl_xor(y, 1, 64);
                    pv[j] = fmaxf(y, y2);
                }
                if (act) {
                    if (st < 7) {
                        uint2 v;
                        v.x = pack2(pv[0], pv[1]);
                        v.y = pack2(pv[2], pv[3]);
                        *(uint2*)&dst[u * 128 + (((4 * wq + q) ^ (u & 15)) * 8) + 4 * h] = v;
                    } else {
                        float4 o = {pv[0], pv[1], pv[2], pv[3]};
                        *(float4*)&out[wq * 32 + 8 * q + 4 * h] = o;
                    }
                }
            }
        }
        __syncthreads();
        Lin = Lp;
    }
}

// ---------------------------------------------------------------------------
extern "C" void kernel_launch(void* const* d_in, const int* in_sizes, int n_in,
                              void* d_out, int out_size, void* d_ws, size_t ws_size,
                              hipStream_t stream) {
    const float* x     = (const float*)d_in[0];   // [524288][128]
    const float* depth = (const float*)d_in[1];   // [32][128]
    const float* W     = (const float*)d_in[2];   // [128][256][2]
    const float* b     = (const float*)d_in[3];   // [128]
    const int*   perm  = (const int*)d_in[4];     // [524288]
    float* out = (float*)d_out;                   // [1][128] fp32

    char* ws = (char*)d_ws;
    float*  Bst = (float*)ws;                                   // 18*128 fp32 (16 KB slot)
    ushort* A   = (ushort*)(ws + 16384);                        // 128*256 bf16 (64 KB)
    ushort* Gx  = (ushort*)(ws + 16384 + 65536);                // 524288*128 bf16 = 128 MB
    ushort* R0  = (ushort*)(ws + 16384 + 65536 + (size_t)134217728);
    ushort* R1  = (ushort*)(ws + 16384 + 65536 + (size_t)134217728 + (size_t)131071 * 256);

    prep_kernel<<<146, 256, 0, stream>>>(W, b, depth, Bst, A);
    convert_kernel<<<8192, 256, 0, stream>>>(x, Gx);

    // (0,1): 524288 -> 131071  (gather from L3-resident Gx)
    pair_fused<<<4096, 256, 0, stream>>>(Gx, perm, A, Bst, R0, 524288, 131071);
    // (2,3): 131071 -> 32767
    pair_fused<<<1024, 256, 0, stream>>>(R0, nullptr, A, Bst + 2 * 128, R1, 131071, 32767);
    // (4,5): 32767 -> 8191
    pair_fused<<<256, 256, 0, stream>>>(R1, nullptr, A, Bst + 4 * 128, R0, 32767, 8191);
    // (6,7): 8191 -> 2047
    pair_fused<<<64, 256, 0, stream>>>(R0, nullptr, A, Bst + 6 * 128, R1, 8191, 2047);
    // (8,9): 2047 -> 511
    pair_fused<<<16, 256, 0, stream>>>(R1, nullptr, A, Bst + 8 * 128, R0, 2047, 511);
    // 10..17: 511 -> 1
    tail_fused<<<1, 512, (255 + 127) * 128 * 2, stream>>>(R0, A, Bst, out);
}

// Round 4
// 543.525 us; speedup vs baseline: 1.1754x; 1.1754x over previous
//
#include <hip/hip_runtime.h>
#include <hip/hip_bf16.h>

// RecursiveNet bf16-MFMA, round 7: revert to r4 base (556 us), single change:
//   tail_fused 256 -> 1024 threads (16 waves: 4-way tile parity x 4-way
//   channel split) to hide LDS/MFMA latency (was 1 wave/SIMD, fully exposed).
// Gather verdict (r5+r6 nulls): pair(0,1) is random-segment-count bound
//   (~524K segments ~= 158 us hardware floor); convert/L3 detour reverted.

typedef __bf16 v8bf __attribute__((ext_vector_type(8)));
typedef float v16f __attribute__((ext_vector_type(16)));

__device__ __forceinline__ ushort f2bf(float f) {
    __hip_bfloat16 h = __float2bfloat16(f);
    return *reinterpret_cast<ushort*>(&h);
}
__device__ __forceinline__ unsigned pack2(float lo, float hi) {
    return (unsigned)f2bf(lo) | ((unsigned)f2bf(hi) << 16);
}
__device__ __forceinline__ float leaky(float y) { return (y >= 0.f) ? y : 0.2f * y; }

#define ZACC {0.f,0.f,0.f,0.f,0.f,0.f,0.f,0.f,0.f,0.f,0.f,0.f,0.f,0.f,0.f,0.f}

// ---------------------------------------------------------------------------
__global__ void bias_kernel(const float* __restrict__ W, const float* __restrict__ b,
                            const float* __restrict__ depth, float* __restrict__ Bst) {
    int i = blockIdx.x, o = threadIdx.x;
    const float* Wo = W + (size_t)o * 512 + 256;
    const float* di = depth + (size_t)i * 128;
    float s = b[o];
#pragma unroll 8
    for (int c = 0; c < 128; ++c) s += di[c] * (Wo[2 * c] + Wo[2 * c + 1]);
    Bst[i * 128 + o] = s;
}

__global__ void repack_kernel(const float* __restrict__ W, ushort* __restrict__ A) {
    int o = blockIdx.x, c = threadIdx.x;
    float v = (c < 128) ? W[(size_t)o * 512 + 2 * c] : W[(size_t)o * 512 + 2 * (c - 128) + 1];
    A[o * 256 + c] = f2bf(v);
}

// ---------------------------------------------------------------------------
#define WAVE_SETUP()                                                          \
    const int tid = threadIdx.x;                                              \
    const int lane = tid & 63;                                                \
    const int w = tid >> 6;                                                   \
    const int n31 = lane & 31;                                                \
    const int h = lane >> 5;                                                  \
    v8bf af[16];                                                              \
    {                                                                         \
        const ushort* Arow = A + (size_t)(w * 32 + n31) * 256 + h * 8;        \
        _Pragma("unroll")                                                     \
        for (int s = 0; s < 16; ++s) af[s] = *(const v8bf*)&Arow[s * 16];     \
    }

#define LOAD_BIAS(dst_, Bs)                                                   \
    float dst_[16];                                                           \
    _Pragma("unroll")                                                         \
    for (int r = 0; r < 16; ++r)                                              \
        dst_[r] = (Bs)[w * 32 + (r & 3) + 8 * (r >> 2) + 4 * h];

// 16 MFMA from a swizzled LDS tile (rows r0_, r1_ local, pre-clamped)
#define MFMA_TILE_LDS(buf, r0_, r1_, acc)                                     \
    {                                                                         \
        const ushort* sp0 = (buf) + (r0_) * 128;                              \
        const ushort* sp1 = (buf) + (r1_) * 128;                              \
        const int mm0 = (r0_) & 15, mm1 = (r1_) & 15;                         \
        _Pragma("unroll")                                                     \
        for (int s = 0; s < 8; ++s)                                           \
            acc = __builtin_amdgcn_mfma_f32_32x32x16_bf16(                    \
                af[s], *(const v8bf*)&sp0[((2 * s + h) ^ mm0) * 8], acc, 0, 0, 0); \
        _Pragma("unroll")                                                     \
        for (int s = 0; s < 8; ++s)                                           \
            acc = __builtin_amdgcn_mfma_f32_32x32x16_bf16(                    \
                af[8 + s], *(const v8bf*)&sp1[((2 * s + h) ^ mm1) * 8], acc, 0, 0, 0); \
    }

// ---------------------------------------------------------------------------
// Fused pair of stages. Block -> 32 outputs of the second stage.
__global__ __launch_bounds__(256)
void pair_fused(const ushort* __restrict__ Xin,   // bf16 [Lin][128] (stage>0)
                const float* __restrict__ x0,     // fp32 [N][128]  (first pair)
                const int* __restrict__ perm,     // [N]            (first pair)
                const ushort* __restrict__ A,     // bf16 [128][256]
                const float* __restrict__ Bst2,   // fp32 [2][128]
                ushort* __restrict__ Y,           // bf16 [Lp2][128]
                int Lin, int Lp2, int stage0) {
    __shared__ __align__(16) ushort xin[132 * 128];  // 33 KB
    __shared__ __align__(16) ushort mid[65 * 128];   // 16.6 KB
    __shared__ int prow[132];

    const int U = blockIdx.x * 32;
    const int t0 = U * 4;

    if (stage0) {
        for (int r = threadIdx.x; r < 132; r += 256)
            prow[r] = perm[min(t0 + r, Lin - 1)];
        __syncthreads();
    }
    for (int idx = threadIdx.x; idx < 132 * 16; idx += 256) {
        int row = idx >> 4, ck = idx & 15;
        int t = min(t0 + row, Lin - 1);
        int dst = row * 128 + ((ck ^ (row & 15)) * 8);
        if (stage0) {
            const float* s = x0 + (size_t)prow[row] * 128 + ck * 8;
            float4 a = *(const float4*)s;
            float4 bq = *(const float4*)(s + 4);
            uint4 v;
            v.x = pack2(a.x, a.y);  v.y = pack2(a.z, a.w);
            v.z = pack2(bq.x, bq.y); v.w = pack2(bq.z, bq.w);
            *(uint4*)&xin[dst] = v;
        } else {
            *(uint4*)&xin[dst] = *(const uint4*)&Xin[(size_t)t * 128 + ck * 8];
        }
    }
    __syncthreads();

    WAVE_SETUP();

    // ---- stage A: 5 tiles -> mid (LDS)
    {
        LOAD_BIAS(bias_r, Bst2);
#pragma unroll
        for (int ti = 0; ti < 5; ++ti) {
            const int p = 32 * ti + n31;
            const int r0 = min(p, 131), r1 = min(p + 1, 131);
            v16f acc = ZACC;
            MFMA_TILE_LDS(xin, r0, r1, acc);
            const int u1 = 16 * ti + (n31 >> 1);
            const bool act = !(lane & 1) && (u1 < 65);
#pragma unroll
            for (int q = 0; q < 4; ++q) {
                float pv[4];
#pragma unroll
                for (int j = 0; j < 4; ++j) {
                    float y = leaky(acc[4 * q + j] + bias_r[4 * q + j]);
                    float y2 = __shfl_xor(y, 1, 64);
                    pv[j] = fmaxf(y, y2);
                }
                if (act) {
                    uint2 v;
                    v.x = pack2(pv[0], pv[1]);
                    v.y = pack2(pv[2], pv[3]);
                    *(uint2*)&mid[u1 * 128 + (((4 * w + q) ^ (u1 & 15)) * 8) + 4 * h] = v;
                }
            }
        }
    }
    __syncthreads();

    // ---- stage B: 2 tiles -> global
    {
        LOAD_BIAS(bias_r, Bst2 + 128);
#pragma unroll
        for (int ti = 0; ti < 2; ++ti) {
            const int p = 32 * ti + n31;
            v16f acc = ZACC;
            MFMA_TILE_LDS(mid, p, p + 1, acc);
            const int u2 = U + 16 * ti + (n31 >> 1);
            const bool act = !(lane & 1) && (u2 < Lp2);
#pragma unroll
            for (int q = 0; q < 4; ++q) {
                float pv[4];
#pragma unroll
                for (int j = 0; j < 4; ++j) {
                    float y = leaky(acc[4 * q + j] + bias_r[4 * q + j]);
                    float y2 = __shfl_xor(y, 1, 64);
                    pv[j] = fmaxf(y, y2);
                }
                if (act) {
                    uint2 v;
                    v.x = pack2(pv[0], pv[1]);
                    v.y = pack2(pv[2], pv[3]);
                    *(uint2*)&Y[(size_t)u2 * 128 + w * 32 + 8 * q + 4 * h] = v;
                }
            }
        }
    }
}

// ---------------------------------------------------------------------------
// Stages 10..17 fused (Lin = 511 -> 1), one block, 16 waves, LDS ping-pong.
// wq = wave&3 : channel quad (which 32 output channels / A rows)
// wp = wave>>2: tile parity  (tiles ti = wp, wp+4, ...)
__global__ __launch_bounds__(1024)
void tail_fused(const ushort* __restrict__ Xg, const ushort* __restrict__ A,
                const float* __restrict__ BstAll, float* __restrict__ out) {
    extern __shared__ __align__(16) ushort tbuf[];
    ushort* buf0 = tbuf;              // 255 rows
    ushort* buf1 = tbuf + 255 * 128;  // 127 rows

    const int tid = threadIdx.x;
    const int lane = tid & 63;
    const int wv = tid >> 6;          // 0..15
    const int w = wv & 3;             // channel quad (feeds af/bias/output macros)
    const int wp = wv >> 2;           // tile parity 0..3
    const int n31 = lane & 31;
    const int h = lane >> 5;
    v8bf af[16];
    {
        const ushort* Arow = A + (size_t)(w * 32 + n31) * 256 + h * 8;
#pragma unroll
        for (int s = 0; s < 16; ++s) af[s] = *(const v8bf*)&Arow[s * 16];
    }

    int Lin = 511;
    for (int st = 0; st < 8; ++st) {
        const int Lp = (Lin - 1) >> 1;
        LOAD_BIAS(bias_r, BstAll + (size_t)(10 + st) * 128);
        ushort* dst = (st & 1) ? buf1 : buf0;
        const ushort* src = (st & 1) ? buf0 : buf1;  // unused for st==0
        const int ntiles = (Lin - 1 + 31) >> 5;
        for (int ti = wp; ti < ntiles; ti += 4) {
            const int t = ti * 32 + n31;
            const int r0 = min(t, Lin - 1), r1 = min(t + 1, Lin - 1);
            v16f acc = ZACC;
            if (st == 0) {
                const ushort* p0 = Xg + (size_t)r0 * 128 + h * 8;
                const ushort* p1 = Xg + (size_t)r1 * 128 + h * 8;
#pragma unroll
                for (int s = 0; s < 8; ++s)
                    acc = __builtin_amdgcn_mfma_f32_32x32x16_bf16(
                        af[s], *(const v8bf*)&p0[s * 16], acc, 0, 0, 0);
#pragma unroll
                for (int s = 0; s < 8; ++s)
                    acc = __builtin_amdgcn_mfma_f32_32x32x16_bf16(
                        af[8 + s], *(const v8bf*)&p1[s * 16], acc, 0, 0, 0);
            } else {
                MFMA_TILE_LDS(src, r0, r1, acc);
            }
            const int u = t >> 1;
            const bool act = !(lane & 1) && (u < Lp);
#pragma unroll
            for (int q = 0; q < 4; ++q) {
                float pv[4];
#pragma unroll
                for (int j = 0; j < 4; ++j) {
                    float y = leaky(acc[4 * q + j] + bias_r[4 * q + j]);
                    float y2 = __shfl_xor(y, 1, 64);
                    pv[j] = fmaxf(y, y2);
                }
                if (act) {
                    if (st < 7) {
                        uint2 v;
                        v.x = pack2(pv[0], pv[1]);
                        v.y = pack2(pv[2], pv[3]);
                        *(uint2*)&dst[u * 128 + (((4 * w + q) ^ (u & 15)) * 8) + 4 * h] = v;
                    } else {
                        float4 o = {pv[0], pv[1], pv[2], pv[3]};
                        *(float4*)&out[w * 32 + 8 * q + 4 * h] = o;
                    }
                }
            }
        }
        __syncthreads();
        Lin = Lp;
    }
}

// ---------------------------------------------------------------------------
extern "C" void kernel_launch(void* const* d_in, const int* in_sizes, int n_in,
                              void* d_out, int out_size, void* d_ws, size_t ws_size,
                              hipStream_t stream) {
    const float* x     = (const float*)d_in[0];   // [524288][128]
    const float* depth = (const float*)d_in[1];   // [32][128]
    const float* W     = (const float*)d_in[2];   // [128][256][2]
    const float* b     = (const float*)d_in[3];   // [128]
    const int*   perm  = (const int*)d_in[4];     // [524288]
    float* out = (float*)d_out;                   // [1][128] fp32

    char* ws = (char*)d_ws;
    float*  Bst = (float*)ws;                                            // 18*128 fp32
    ushort* A   = (ushort*)(ws + 16384);                                 // 128*256 bf16
    ushort* R0  = (ushort*)(ws + 16384 + 65536);                         // 131071 rows max
    ushort* R1  = (ushort*)(ws + 16384 + 65536 + (size_t)131071 * 256);  // 32767 rows max

    bias_kernel<<<18, 128, 0, stream>>>(W, b, depth, Bst);
    repack_kernel<<<128, 256, 0, stream>>>(W, A);

    // (0,1): 524288 -> 131071
    pair_fused<<<4096, 256, 0, stream>>>(nullptr, x, perm, A, Bst, R0,
                                         524288, 131071, 1);
    // (2,3): 131071 -> 32767
    pair_fused<<<1024, 256, 0, stream>>>(R0, nullptr, nullptr, A, Bst + 2 * 128, R1,
                                         131071, 32767, 0);
    // (4,5): 32767 -> 8191
    pair_fused<<<256, 256, 0, stream>>>(R1, nullptr, nullptr, A, Bst + 4 * 128, R0,
                                        32767, 8191, 0);
    // (6,7): 8191 -> 2047
    pair_fused<<<64, 256, 0, stream>>>(R0, nullptr, nullptr, A, Bst + 6 * 128, R1,
                                       8191, 2047, 0);
    // (8,9): 2047 -> 511
    pair_fused<<<16, 256, 0, stream>>>(R1, nullptr, nullptr, A, Bst + 8 * 128, R0,
                                       2047, 511, 0);
    // 10..17: 511 -> 1
    tail_fused<<<1, 1024, (255 + 127) * 128 * 2, stream>>>(R0, A, Bst, out);
}